// Round 6
// baseline (215.504 us; speedup 1.0000x reference)
//
#include <hip/hip_runtime.h>
#include <math.h>

#define NH 8
#define NL 4
#define NP 8
#define CDIM 256
#define NQ 10000
#define BS 2
#define NV 19560

__constant__ int LVL_H[NL]     = {92, 46, 23, 12};
__constant__ int LVL_W[NL]     = {160, 80, 40, 20};
__constant__ int LVL_START[NL] = {0, 14720, 18400, 19320};

typedef __attribute__((ext_vector_type(8))) short short8;
typedef __attribute__((ext_vector_type(4))) float f32x4;
typedef __attribute__((ext_vector_type(2))) _Float16 half2v;
typedef __attribute__((ext_vector_type(4))) _Float16 half4v;

__device__ __forceinline__ unsigned short f2bf(float f) {
    unsigned int u = __float_as_uint(f);
    u += 0x7fffu + ((u >> 16) & 1u);   // RNE
    return (unsigned short)(u >> 16);
}

__device__ __forceinline__ unsigned short f2h_bits(float f) {
    return __builtin_bit_cast(unsigned short, (_Float16)f);
}

// ---------------------------------------------------------------------------
// All prep in ONE dispatch: value->bf16, query->bf16, weight transpose/concat.
// blocks [0,9780): value; [9780,14780): query; [14780,15805): weights/bias.
// ---------------------------------------------------------------------------
__global__ __launch_bounds__(256) void prep_all(
    const float* __restrict__ value, const float* __restrict__ query,
    const float* __restrict__ Wv,
    const float* __restrict__ Woff, const float* __restrict__ boff,
    const float* __restrict__ Wattn, const float* __restrict__ battn,
    unsigned short* __restrict__ valuebf, unsigned short* __restrict__ querybf,
    unsigned short* __restrict__ BvalT, unsigned short* __restrict__ BcatT,
    float* __restrict__ biascat)
{
    const int bid = blockIdx.x;
    const int t   = threadIdx.x;
    if (bid < 9780) {
        const int i = bid * 256 + t;
        const float4 f = ((const float4*)value)[i];
        ushort4 o;
        o.x = f2bf(f.x); o.y = f2bf(f.y); o.z = f2bf(f.z); o.w = f2bf(f.w);
        ((ushort4*)valuebf)[i] = o;
    } else if (bid < 14780) {
        const int i = (bid - 9780) * 256 + t;
        const float4 f = ((const float4*)query)[i];
        ushort4 o;
        o.x = f2bf(f.x); o.y = f2bf(f.y); o.z = f2bf(f.z); o.w = f2bf(f.w);
        ((ushort4*)querybf)[i] = o;
    } else {
        const int n = bid - 14780;
        if (n < 256) {
            BvalT[n * 256 + t] = f2bf(Wv[t * 256 + n]);
        } else if (n < 1024) {
            const int m = n - 256;
            const float v = (m < 512) ? Woff[t * 512 + m]
                                      : Wattn[t * 256 + (m - 512)];
            BcatT[m * 256 + t] = f2bf(v);
        } else {
            #pragma unroll
            for (int s = 0; s < 3; s++) {
                const int i = s * 256 + t;
                biascat[i] = (i < 512) ? boff[i] : battn[i - 512];
            }
        }
    }
}

// ---------------------------------------------------------------------------
// BOTH GEMMs in one dispatch. bf16 A [M][256], B^T [N][256], BK=32,
// 128x128 tile. MFMA operands SWAPPED -> reg quad holds 4 consecutive
// COLUMNS: epilogue is 8B-contiguous f16 stores.
// blocks [0,612): value proj -> head-major f16 vproj (b,h,pix,32)
// blocks [612,1554): query @ Wcat -> f16 offcat (row,768)
// ---------------------------------------------------------------------------
#define AST 130
__global__ __launch_bounds__(256) void gemm_all(
    const unsigned short* __restrict__ valuebf,
    const unsigned short* __restrict__ BvalT,
    const float* __restrict__ b_value, _Float16* __restrict__ vproj,
    const unsigned short* __restrict__ querybf,
    const unsigned short* __restrict__ BcatT,
    const float* __restrict__ biascat, _Float16* __restrict__ offcat)
{
    __shared__ short8 Al[4 * AST];
    __shared__ short8 Bl[4 * AST];

    const int bid = blockIdx.x;
    const bool modeV = bid < 612;

    const unsigned short* A;
    const unsigned short* Bt;
    const float* bias;
    int M, N, rowBase, colBase;
    if (modeV) {
        A = valuebf; Bt = BvalT; bias = b_value;
        M = BS * NV; N = 256;
        rowBase = (bid >> 1) * 128; colBase = (bid & 1) * 128;
    } else {
        const int b2 = bid - 612;
        A = querybf; Bt = BcatT; bias = biascat;
        M = BS * NQ; N = 768;
        rowBase = (b2 / 6) * 128; colBase = (b2 % 6) * 128;
    }

    const int t = threadIdx.x;
    const int w  = t >> 6;
    const int l  = t & 63;
    const int wm = (w >> 1) * 64;
    const int wn = (w & 1) * 64;
    const int row16 = l & 15;
    const int kg    = l >> 4;

    const int sr = t >> 1;
    const int sh = t & 1;

    f32x4 acc[4][4] = {};

    for (int k0 = 0; k0 < 256; k0 += 32) {
        {   // A tile
            const int grow = rowBase + sr;
            short8 v0 = {}, v1 = {};
            if (grow < M) {
                const unsigned short* ap = A + (size_t)grow * 256 + k0 + sh * 16;
                v0 = *(const short8*)ap;
                v1 = *(const short8*)(ap + 8);
            }
            Al[(sh * 2 + 0) * AST + sr] = v0;
            Al[(sh * 2 + 1) * AST + sr] = v1;
        }
        {   // B tile (B^T: always in-range)
            const unsigned short* bp = Bt + (size_t)(colBase + sr) * 256 + k0 + sh * 16;
            Bl[(sh * 2 + 0) * AST + sr] = *(const short8*)bp;
            Bl[(sh * 2 + 1) * AST + sr] = *(const short8*)(bp + 8);
        }
        __syncthreads();

        short8 af[4], bfr[4];
        #pragma unroll
        for (int i = 0; i < 4; i++) af[i] = Al[kg * AST + wm + i * 16 + row16];
        #pragma unroll
        for (int j = 0; j < 4; j++) bfr[j] = Bl[kg * AST + wn + j * 16 + row16];
        // swapped operands: D "row" = col-of-C, reg quad = 4 consecutive cols
        #pragma unroll
        for (int i = 0; i < 4; i++)
            #pragma unroll
            for (int j = 0; j < 4; j++)
                acc[i][j] = __builtin_amdgcn_mfma_f32_16x16x32_bf16(
                    bfr[j], af[i], acc[i][j], 0, 0, 0);
        __syncthreads();
    }

    // epilogue (swapped layout): row = base + i*16 + (l&15),
    //                            col = base + j*16 + (l>>4)*4 + reg
    const int m16 = l & 15;
    const int q4  = (l >> 4) * 4;
    #pragma unroll
    for (int i = 0; i < 4; i++) {
        const int row = rowBase + wm + i * 16 + m16;
        if (row >= M) continue;
        #pragma unroll
        for (int j = 0; j < 4; j++) {
            const int col0 = colBase + wn + j * 16 + q4;
            const float4 bv = *(const float4*)&bias[col0];
            half4v o;
            o[0] = (_Float16)(acc[i][j][0] + bv.x);
            o[1] = (_Float16)(acc[i][j][1] + bv.y);
            o[2] = (_Float16)(acc[i][j][2] + bv.z);
            o[3] = (_Float16)(acc[i][j][3] + bv.w);
            _Float16* dst;
            if (modeV) {
                const int b   = (row >= NV) ? 1 : 0;
                const int pix = row - b * NV;
                const int h   = col0 >> 5;
                const int ch  = col0 & 31;
                dst = vproj + ((size_t)(b * NH + h) * NV + pix) * 32 + ch;
            } else {
                dst = offcat + (size_t)row * 768 + col0;
            }
            *(half4v*)dst = o;
        }
    }
}

// ---------------------------------------------------------------------------
// Fused softmax + sampling + aggregation, (b,h)-partitioned for L2 locality.
// Descriptors are 8 B: {pixel byte-offset, wL:f16 | wR:f16}. Phase B:
// ds_read_b64 (broadcast) + 32-bit voffset saddr load + 4 v_pk_fma_f16.
// ---------------------------------------------------------------------------
__global__ __launch_bounds__(256) void sample_kernel(
    const _Float16* __restrict__ vproj,  // (BS, NH, NV, 32) f16
    const _Float16* __restrict__ offcat, // (BS*NQ, 768) f16 off|logits
    const float* __restrict__ refpts,    // (BS, NQ, 4, 2)
    float* __restrict__ out)             // (BS*NQ, 256)
{
    const int bid = blockIdx.x;
    const int h   = bid & 7;             // XCD-affine head
    const int g   = bid >> 3;
    const int b   = g & 1;
    const int q0  = (g >> 1) * 8;
    const int t   = threadIdx.x;

    __shared__ uint2 desc[8 * 64];       // {byteoff, wL|wR<<16}

    const int qi = t >> 5, j = t & 31;
    const int qrow = b * NQ + q0 + qi;

    // ---------------- Phase A ----------------
    {
        const int lv = j >> 3, p = j & 7;

        float logit = (float)offcat[(size_t)qrow * 768 + 512 + h * 32 + j];
        float m = logit;
        #pragma unroll
        for (int s = 16; s > 0; s >>= 1) m = fmaxf(m, __shfl_xor(m, s, 32));
        float e = __expf(logit - m);
        float ssum = e;
        #pragma unroll
        for (int s = 16; s > 0; s >>= 1) ssum += __shfl_xor(ssum, s, 32);
        const float aw = e / ssum;

        const int Wl = LVL_W[lv], Hl = LVL_H[lv], st = LVL_START[lv];
        const float offx = (float)offcat[(size_t)qrow * 768 + h * 64 + j * 2];
        const float offy = (float)offcat[(size_t)qrow * 768 + h * 64 + j * 2 + 1];

        const int z = p & 3;
        const float rx = refpts[((size_t)qrow * 4 + z) * 2];
        const float ry = refpts[((size_t)qrow * 4 + z) * 2 + 1];

        const float x = fmaf(rx, (float)Wl, offx) - 0.5f;
        const float y = fmaf(ry, (float)Hl, offy) - 0.5f;
        const float x0f = floorf(x), y0f = floorf(y);
        const float wx = x - x0f, wy = y - y0f;
        const int x0 = (int)x0f, y0 = (int)y0f;

        const int xb = min(max(x0, 0), Wl - 2);
        const float wl = (x0 >= 0 && x0 < Wl)          ? (1.f - wx) : 0.f;
        const float wr = (x0 + 1 >= 0 && x0 + 1 < Wl)  ? wx         : 0.f;
        const float wA = (x0 == xb) ? wl : ((x0 + 1 == xb) ? wr : 0.f);
        const float wB = (x0 == xb) ? wr : ((x0 == xb + 1) ? wl : 0.f);

        #pragma unroll
        for (int r = 0; r < 2; r++) {
            const int yy = y0 + r;
            const float rwv = (yy >= 0 && yy < Hl)
                            ? (r ? wy : (1.f - wy)) * aw : 0.f;
            const int iy = min(max(yy, 0), Hl - 1);
            uint2 d;
            d.x = (unsigned)((st + iy * Wl + xb) * 64);   // 64 B per pixel
            d.y = (unsigned)f2h_bits(wA * rwv)
                | ((unsigned)f2h_bits(wB * rwv) << 16);
            desc[qi * 64 + j * 2 + r] = d;
        }
    }
    __syncthreads();

    // ---------------- Phase B ----------------
    const int lane = t & 31;
    const int grp  = lane >> 3;          // descriptor stride group
    const int sub  = lane & 7;
    const int pix  = sub >> 2;           // left/right x-column
    const int chq  = sub & 3;            // channel quad (8 ch = 16 B)

    const char* slab = (const char*)(vproj + (size_t)(b * NH + h) * NV * 32);
    const unsigned laneoff = (unsigned)(pix * 64 + chq * 16);
    const int shamt = pix * 16;
    const uint2* dq = &desc[qi * 64];

    half2v a0 = {}, a1 = {}, a2 = {}, a3 = {};
    #pragma unroll
    for (int i = 0; i < 16; i++) {
        const uint2 dsc = dq[i * 4 + grp];
        const unsigned off = dsc.x + laneoff;
        const unsigned wsu = (dsc.y >> shamt) & 0xffffu;
        const half2v wv = __builtin_bit_cast(half2v, wsu | (wsu << 16));
        const uint4 u = *(const uint4*)(slab + off);
        a0 += wv * __builtin_bit_cast(half2v, u.x);   // v_pk_fma_f16
        a1 += wv * __builtin_bit_cast(half2v, u.y);
        a2 += wv * __builtin_bit_cast(half2v, u.z);
        a3 += wv * __builtin_bit_cast(half2v, u.w);
    }

    float accf[8] = {(float)a0[0], (float)a0[1], (float)a1[0], (float)a1[1],
                     (float)a2[0], (float)a2[1], (float)a3[0], (float)a3[1]};
    #pragma unroll
    for (int s = 4; s <= 16; s <<= 1)
        #pragma unroll
        for (int e = 0; e < 8; e++) accf[e] += __shfl_xor(accf[e], s, 32);

    if ((lane & 0x1C) == 0) {            // lanes 0..3 = chq
        float* op = out + (size_t)qrow * 256 + h * 32 + chq * 8;
        *(float4*)op       = make_float4(accf[0], accf[1], accf[2], accf[3]);
        *(float4*)(op + 4) = make_float4(accf[4], accf[5], accf[6], accf[7]);
    }
}

// ---------------------------------------------------------------------------
extern "C" void kernel_launch(void* const* d_in, const int* in_sizes, int n_in,
                              void* d_out, int out_size, void* d_ws, size_t ws_size,
                              hipStream_t stream)
{
    const float* query   = (const float*)d_in[0];
    const float* value   = (const float*)d_in[1];
    const float* refpts  = (const float*)d_in[2];
    const float* W_value = (const float*)d_in[4];
    const float* b_value = (const float*)d_in[5];
    const float* W_off   = (const float*)d_in[6];
    const float* b_off   = (const float*)d_in[7];
    const float* W_attn  = (const float*)d_in[8];
    const float* b_attn  = (const float*)d_in[9];

    char* ws = (char*)d_ws;                       // total 81.55 MB
    _Float16*       vproj   = (_Float16*)(ws);                    // 20,029,440
    unsigned short* valuebf = (unsigned short*)(ws + 20029440);   // 20,029,440
    unsigned short* querybf = (unsigned short*)(ws + 40058880);   // 10,240,000
    _Float16*       offcat  = (_Float16*)(ws + 50298880);         // 30,720,000
    unsigned short* BvalT   = (unsigned short*)(ws + 81018880);   //    131,072
    unsigned short* BcatT   = (unsigned short*)(ws + 81149952);   //    393,216
    float*          biascat = (float*)(ws + 81543168);            //      3,072

    const dim3 blk(256);

    prep_all<<<dim3(15805), blk, 0, stream>>>(
        value, query, W_value, W_off, b_off, W_attn, b_attn,
        valuebf, querybf, BvalT, BcatT, biascat);

    gemm_all<<<dim3(1554), blk, 0, stream>>>(
        valuebf, BvalT, b_value, vproj,
        querybf, BcatT, biascat, offcat);

    sample_kernel<<<dim3(BS * NQ), blk, 0, stream>>>(
        vproj, offcat, refpts, (float*)d_out);
}

// Round 7
// 215.490 us; speedup vs baseline: 1.0001x; 1.0001x over previous
//
#include <hip/hip_runtime.h>
#include <math.h>

#define NH 8
#define NL 4
#define NP 8
#define CDIM 256
#define NQ 10000
#define BS 2
#define NV 19560

__constant__ int LVL_H[NL]     = {92, 46, 23, 12};
__constant__ int LVL_W[NL]     = {160, 80, 40, 20};
__constant__ int LVL_START[NL] = {0, 14720, 18400, 19320};

typedef __attribute__((ext_vector_type(8))) short short8;
typedef __attribute__((ext_vector_type(4))) float f32x4;
typedef __attribute__((ext_vector_type(2))) _Float16 half2v;
typedef __attribute__((ext_vector_type(4))) _Float16 half4v;

__device__ __forceinline__ unsigned short f2bf(float f) {
    unsigned int u = __float_as_uint(f);
    u += 0x7fffu + ((u >> 16) & 1u);   // RNE
    return (unsigned short)(u >> 16);
}

__device__ __forceinline__ unsigned f2h_dup(float f) {
    const unsigned short h = __builtin_bit_cast(unsigned short, (_Float16)f);
    return (unsigned)h | ((unsigned)h << 16);
}

// ---------------------------------------------------------------------------
// All prep in ONE dispatch: value->bf16, query->bf16, weight transpose/concat.
// ---------------------------------------------------------------------------
__global__ __launch_bounds__(256) void prep_all(
    const float* __restrict__ value, const float* __restrict__ query,
    const float* __restrict__ Wv,
    const float* __restrict__ Woff, const float* __restrict__ boff,
    const float* __restrict__ Wattn, const float* __restrict__ battn,
    unsigned short* __restrict__ valuebf, unsigned short* __restrict__ querybf,
    unsigned short* __restrict__ BvalT, unsigned short* __restrict__ BcatT,
    float* __restrict__ biascat)
{
    const int bid = blockIdx.x;
    const int t   = threadIdx.x;
    if (bid < 9780) {
        const int i = bid * 256 + t;
        const float4 f = ((const float4*)value)[i];
        ushort4 o;
        o.x = f2bf(f.x); o.y = f2bf(f.y); o.z = f2bf(f.z); o.w = f2bf(f.w);
        ((ushort4*)valuebf)[i] = o;
    } else if (bid < 14780) {
        const int i = (bid - 9780) * 256 + t;
        const float4 f = ((const float4*)query)[i];
        ushort4 o;
        o.x = f2bf(f.x); o.y = f2bf(f.y); o.z = f2bf(f.z); o.w = f2bf(f.w);
        ((ushort4*)querybf)[i] = o;
    } else {
        const int n = bid - 14780;
        if (n < 256) {
            BvalT[n * 256 + t] = f2bf(Wv[t * 256 + n]);
        } else if (n < 1024) {
            const int m = n - 256;
            const float v = (m < 512) ? Woff[t * 512 + m]
                                      : Wattn[t * 256 + (m - 512)];
            BcatT[m * 256 + t] = f2bf(v);
        } else {
            #pragma unroll
            for (int s = 0; s < 3; s++) {
                const int i = s * 256 + t;
                biascat[i] = (i < 512) ? boff[i] : battn[i - 512];
            }
        }
    }
}

// ---------------------------------------------------------------------------
// BOTH GEMMs in one dispatch. bf16 A [M][256], B^T [N][256], BK=32,
// 128x128 tile, swapped MFMA operands -> 8B-contiguous f16 epilogue stores.
// blocks [0,612): value proj -> head-major f16 vproj (b,h,pix,32)
// blocks [612,1554): query @ Wcat -> f16 offcat (row,768)
// ---------------------------------------------------------------------------
#define AST 130
__global__ __launch_bounds__(256) void gemm_all(
    const unsigned short* __restrict__ valuebf,
    const unsigned short* __restrict__ BvalT,
    const float* __restrict__ b_value, _Float16* __restrict__ vproj,
    const unsigned short* __restrict__ querybf,
    const unsigned short* __restrict__ BcatT,
    const float* __restrict__ biascat, _Float16* __restrict__ offcat)
{
    __shared__ short8 Al[4 * AST];
    __shared__ short8 Bl[4 * AST];

    const int bid = blockIdx.x;
    const bool modeV = bid < 612;

    const unsigned short* A;
    const unsigned short* Bt;
    const float* bias;
    int M, N, rowBase, colBase;
    if (modeV) {
        A = valuebf; Bt = BvalT; bias = b_value;
        M = BS * NV; N = 256;
        rowBase = (bid >> 1) * 128; colBase = (bid & 1) * 128;
    } else {
        const int b2 = bid - 612;
        A = querybf; Bt = BcatT; bias = biascat;
        M = BS * NQ; N = 768;
        rowBase = (b2 / 6) * 128; colBase = (b2 % 6) * 128;
    }

    const int t = threadIdx.x;
    const int w  = t >> 6;
    const int l  = t & 63;
    const int wm = (w >> 1) * 64;
    const int wn = (w & 1) * 64;
    const int row16 = l & 15;
    const int kg    = l >> 4;

    const int sr = t >> 1;
    const int sh = t & 1;

    f32x4 acc[4][4] = {};

    for (int k0 = 0; k0 < 256; k0 += 32) {
        {   // A tile
            const int grow = rowBase + sr;
            short8 v0 = {}, v1 = {};
            if (grow < M) {
                const unsigned short* ap = A + (size_t)grow * 256 + k0 + sh * 16;
                v0 = *(const short8*)ap;
                v1 = *(const short8*)(ap + 8);
            }
            Al[(sh * 2 + 0) * AST + sr] = v0;
            Al[(sh * 2 + 1) * AST + sr] = v1;
        }
        {   // B tile (B^T: always in-range)
            const unsigned short* bp = Bt + (size_t)(colBase + sr) * 256 + k0 + sh * 16;
            Bl[(sh * 2 + 0) * AST + sr] = *(const short8*)bp;
            Bl[(sh * 2 + 1) * AST + sr] = *(const short8*)(bp + 8);
        }
        __syncthreads();

        short8 af[4], bfr[4];
        #pragma unroll
        for (int i = 0; i < 4; i++) af[i] = Al[kg * AST + wm + i * 16 + row16];
        #pragma unroll
        for (int j = 0; j < 4; j++) bfr[j] = Bl[kg * AST + wn + j * 16 + row16];
        #pragma unroll
        for (int i = 0; i < 4; i++)
            #pragma unroll
            for (int j = 0; j < 4; j++)
                acc[i][j] = __builtin_amdgcn_mfma_f32_16x16x32_bf16(
                    bfr[j], af[i], acc[i][j], 0, 0, 0);
        __syncthreads();
    }

    const int m16 = l & 15;
    const int q4  = (l >> 4) * 4;
    #pragma unroll
    for (int i = 0; i < 4; i++) {
        const int row = rowBase + wm + i * 16 + m16;
        if (row >= M) continue;
        #pragma unroll
        for (int j = 0; j < 4; j++) {
            const int col0 = colBase + wn + j * 16 + q4;
            const float4 bv = *(const float4*)&bias[col0];
            half4v o;
            o[0] = (_Float16)(acc[i][j][0] + bv.x);
            o[1] = (_Float16)(acc[i][j][1] + bv.y);
            o[2] = (_Float16)(acc[i][j][2] + bv.z);
            o[3] = (_Float16)(acc[i][j][3] + bv.w);
            _Float16* dst;
            if (modeV) {
                const int b   = (row >= NV) ? 1 : 0;
                const int pix = row - b * NV;
                const int h   = col0 >> 5;
                const int ch  = col0 & 31;
                dst = vproj + ((size_t)(b * NH + h) * NV + pix) * 32 + ch;
            } else {
                dst = offcat + (size_t)row * 768 + col0;
            }
            *(half4v*)dst = o;
        }
    }
}

// ---------------------------------------------------------------------------
// Fused softmax + sampling + aggregation, (b,h)-partitioned for L2 locality.
// Descriptors pre-resolved PER X-COLUMN: {byteoff (incl. pix), wdup f16x2}.
// Phase B iter: ds_read_b64 -> 1 v_add -> global uint4 -> 4 v_pk_fma_f16,
// batched 4-wide for memory-level parallelism. No max-pass in softmax
// (mathematically identical). f16 packed cross-lane reduce.
// ---------------------------------------------------------------------------
__global__ __launch_bounds__(256, 8) void sample_kernel(
    const _Float16* __restrict__ vproj,  // (BS, NH, NV, 32) f16
    const _Float16* __restrict__ offcat, // (BS*NQ, 768) f16 off|logits
    const float* __restrict__ refpts,    // (BS, NQ, 4, 2)
    float* __restrict__ out)             // (BS*NQ, 256)
{
    const int bid = blockIdx.x;
    const int h   = bid & 7;             // XCD-affine head
    const int g   = bid >> 3;
    const int b   = g & 1;
    const int q0  = (g >> 1) * 8;
    const int t   = threadIdx.x;

    __shared__ uint2 desc[8 * 64 * 2];   // [(qi*64 + d)*2 + pix]

    const int qi = t >> 5, j = t & 31;
    const int qrow = b * NQ + q0 + qi;

    // ---------------- Phase A ----------------
    {
        const int lv = j >> 3, p = j & 7;

        // softmax without max-pass (|logit| small; exp2-based, f32-safe)
        const float logit = (float)offcat[(size_t)qrow * 768 + 512 + h * 32 + j];
        const float e = __expf(logit);
        float ssum = e;
        #pragma unroll
        for (int s = 16; s > 0; s >>= 1) ssum += __shfl_xor(ssum, s, 32);
        const float aw = e / ssum;

        const int Wl = LVL_W[lv], Hl = LVL_H[lv], st = LVL_START[lv];
        const uint oxy = *(const uint*)(offcat + (size_t)qrow * 768 + h * 64 + j * 2);
        const float offx = (float)__builtin_bit_cast(half2v, oxy)[0];
        const float offy = (float)__builtin_bit_cast(half2v, oxy)[1];

        const int z = p & 3;
        const float rx = refpts[((size_t)qrow * 4 + z) * 2];
        const float ry = refpts[((size_t)qrow * 4 + z) * 2 + 1];

        const float x = fmaf(rx, (float)Wl, offx) - 0.5f;
        const float y = fmaf(ry, (float)Hl, offy) - 0.5f;
        const float x0f = floorf(x), y0f = floorf(y);
        const float wx = x - x0f, wy = y - y0f;
        const int x0 = (int)x0f, y0 = (int)y0f;

        const int xb = min(max(x0, 0), Wl - 2);
        const float wl = (x0 >= 0 && x0 < Wl)          ? (1.f - wx) : 0.f;
        const float wr = (x0 + 1 >= 0 && x0 + 1 < Wl)  ? wx         : 0.f;
        const float wA = (x0 == xb) ? wl : ((x0 + 1 == xb) ? wr : 0.f);
        const float wB = (x0 == xb) ? wr : ((x0 == xb + 1) ? wl : 0.f);

        #pragma unroll
        for (int r = 0; r < 2; r++) {
            const int yy = y0 + r;
            const float rwv = (yy >= 0 && yy < Hl)
                            ? (r ? wy : (1.f - wy)) * aw : 0.f;
            const int iy = min(max(yy, 0), Hl - 1);
            const unsigned base = (unsigned)((st + iy * Wl + xb) * 64);
            const int d = qi * 64 + j * 2 + r;
            uint2 d0, d1;
            d0.x = base;      d0.y = f2h_dup(wA * rwv);
            d1.x = base + 64; d1.y = f2h_dup(wB * rwv);
            desc[d * 2 + 0] = d0;
            desc[d * 2 + 1] = d1;
        }
    }
    __syncthreads();

    // ---------------- Phase B ----------------
    const int lane = t & 31;
    const int grp  = lane >> 3;          // descriptor stride group (bits 3-4)
    const int pix  = (lane >> 2) & 1;    // x-column (bit 2)
    const int chq  = lane & 3;           // channel quad (bits 0-1)

    const char* slab = (const char*)(vproj + (size_t)(b * NH + h) * NV * 32);
    const unsigned laneoff = (unsigned)(chq * 16);
    const uint2* dq = &desc[(qi * 64) * 2 + pix];

    half2v a0 = {}, a1 = {}, a2 = {}, a3 = {};
    #pragma unroll
    for (int i0 = 0; i0 < 16; i0 += 4) {
        uint2 d4[4];
        #pragma unroll
        for (int u = 0; u < 4; u++)
            d4[u] = dq[((i0 + u) * 4 + grp) * 2];
        uint4 v4[4];
        #pragma unroll
        for (int u = 0; u < 4; u++)
            v4[u] = *(const uint4*)(slab + (d4[u].x + laneoff));
        #pragma unroll
        for (int u = 0; u < 4; u++) {
            const half2v wv = __builtin_bit_cast(half2v, d4[u].y);
            a0 += wv * __builtin_bit_cast(half2v, v4[u].x);  // v_pk_fma_f16
            a1 += wv * __builtin_bit_cast(half2v, v4[u].y);
            a2 += wv * __builtin_bit_cast(half2v, v4[u].z);
            a3 += wv * __builtin_bit_cast(half2v, v4[u].w);
        }
    }

    // packed f16 reduce over bits 2,3,4 (pix + grp)
    #pragma unroll
    for (int s = 4; s <= 16; s <<= 1) {
        a0 += __builtin_bit_cast(half2v,
              __shfl_xor(__builtin_bit_cast(unsigned, a0), s, 32));
        a1 += __builtin_bit_cast(half2v,
              __shfl_xor(__builtin_bit_cast(unsigned, a1), s, 32));
        a2 += __builtin_bit_cast(half2v,
              __shfl_xor(__builtin_bit_cast(unsigned, a2), s, 32));
        a3 += __builtin_bit_cast(half2v,
              __shfl_xor(__builtin_bit_cast(unsigned, a3), s, 32));
    }

    if ((lane & 0x1C) == 0) {            // lanes 0..3 = chq
        float* op = out + (size_t)qrow * 256 + h * 32 + chq * 8;
        *(float4*)op = make_float4((float)a0[0], (float)a0[1],
                                   (float)a1[0], (float)a1[1]);
        *(float4*)(op + 4) = make_float4((float)a2[0], (float)a2[1],
                                         (float)a3[0], (float)a3[1]);
    }
}

// ---------------------------------------------------------------------------
extern "C" void kernel_launch(void* const* d_in, const int* in_sizes, int n_in,
                              void* d_out, int out_size, void* d_ws, size_t ws_size,
                              hipStream_t stream)
{
    const float* query   = (const float*)d_in[0];
    const float* value   = (const float*)d_in[1];
    const float* refpts  = (const float*)d_in[2];
    const float* W_value = (const float*)d_in[4];
    const float* b_value = (const float*)d_in[5];
    const float* W_off   = (const float*)d_in[6];
    const float* b_off   = (const float*)d_in[7];
    const float* W_attn  = (const float*)d_in[8];
    const float* b_attn  = (const float*)d_in[9];

    char* ws = (char*)d_ws;                       // total 81.55 MB
    _Float16*       vproj   = (_Float16*)(ws);                    // 20,029,440
    unsigned short* valuebf = (unsigned short*)(ws + 20029440);   // 20,029,440
    unsigned short* querybf = (unsigned short*)(ws + 40058880);   // 10,240,000
    _Float16*       offcat  = (_Float16*)(ws + 50298880);         // 30,720,000
    unsigned short* BvalT   = (unsigned short*)(ws + 81018880);   //    131,072
    unsigned short* BcatT   = (unsigned short*)(ws + 81149952);   //    393,216
    float*          biascat = (float*)(ws + 81543168);            //      3,072

    const dim3 blk(256);

    prep_all<<<dim3(15805), blk, 0, stream>>>(
        value, query, W_value, W_off, b_off, W_attn, b_attn,
        valuebf, querybf, BvalT, BcatT, biascat);

    gemm_all<<<dim3(1554), blk, 0, stream>>>(
        valuebf, BvalT, b_value, vproj,
        querybf, BcatT, biascat, offcat);

    sample_kernel<<<dim3(BS * NQ), blk, 0, stream>>>(
        vproj, offcat, refpts, (float*)d_out);
}

// Round 8
// 211.468 us; speedup vs baseline: 1.0191x; 1.0190x over previous
//
#include <hip/hip_runtime.h>
#include <math.h>

#define NH 8
#define NL 4
#define NP 8
#define CDIM 256
#define NQ 10000
#define BS 2
#define NV 19560

__constant__ int LVL_H[NL]     = {92, 46, 23, 12};
__constant__ int LVL_W[NL]     = {160, 80, 40, 20};
__constant__ int LVL_START[NL] = {0, 14720, 18400, 19320};

typedef __attribute__((ext_vector_type(8))) short short8;
typedef __attribute__((ext_vector_type(4))) float f32x4;
typedef __attribute__((ext_vector_type(2))) _Float16 half2v;
typedef __attribute__((ext_vector_type(4))) _Float16 half4v;

__device__ __forceinline__ unsigned short f2bf(float f) {
    unsigned int u = __float_as_uint(f);
    u += 0x7fffu + ((u >> 16) & 1u);   // RNE
    return (unsigned short)(u >> 16);
}

__device__ __forceinline__ unsigned f2h_dup(float f) {
    const unsigned short h = __builtin_bit_cast(unsigned short, (_Float16)f);
    return (unsigned)h | ((unsigned)h << 16);
}

// ---------------------------------------------------------------------------
// Prep: query->bf16 (blocks [0,5000)) + weight transpose/concat ([5000,6025)).
// value is converted inline in the GEMM (saves its HBM round trip).
// ---------------------------------------------------------------------------
__global__ __launch_bounds__(256) void prep_all(
    const float* __restrict__ query,
    const float* __restrict__ Wv,
    const float* __restrict__ Woff, const float* __restrict__ boff,
    const float* __restrict__ Wattn, const float* __restrict__ battn,
    unsigned short* __restrict__ querybf,
    unsigned short* __restrict__ BvalT, unsigned short* __restrict__ BcatT,
    float* __restrict__ biascat)
{
    const int bid = blockIdx.x;
    const int t   = threadIdx.x;
    if (bid < 5000) {
        const int i = bid * 256 + t;
        const float4 f = ((const float4*)query)[i];
        ushort4 o;
        o.x = f2bf(f.x); o.y = f2bf(f.y); o.z = f2bf(f.z); o.w = f2bf(f.w);
        ((ushort4*)querybf)[i] = o;
    } else {
        const int n = bid - 5000;
        if (n < 256) {
            BvalT[n * 256 + t] = f2bf(Wv[t * 256 + n]);
        } else if (n < 1024) {
            const int m = n - 256;
            const float v = (m < 512) ? Woff[t * 512 + m]
                                      : Wattn[t * 256 + (m - 512)];
            BcatT[m * 256 + t] = f2bf(v);
        } else {
            #pragma unroll
            for (int s = 0; s < 3; s++) {
                const int i = s * 256 + t;
                biascat[i] = (i < 512) ? boff[i] : battn[i - 512];
            }
        }
    }
}

// ---------------------------------------------------------------------------
// BOTH GEMMs in one dispatch. 128x128 tile, BK=32, swapped MFMA operands ->
// 8B-contiguous f16 epilogue stores.
// blocks [0,612): A = value (fp32, inline cvt) -> head-major f16 vproj
// blocks [612,1554): A = querybf (bf16) @ BcatT -> f16 offcat (row,768)
// ---------------------------------------------------------------------------
#define AST 130
__global__ __launch_bounds__(256) void gemm_all(
    const float* __restrict__ valueF,
    const unsigned short* __restrict__ BvalT,
    const float* __restrict__ b_value, _Float16* __restrict__ vproj,
    const unsigned short* __restrict__ querybf,
    const unsigned short* __restrict__ BcatT,
    const float* __restrict__ biascat, _Float16* __restrict__ offcat)
{
    __shared__ short8 Al[4 * AST];
    __shared__ short8 Bl[4 * AST];

    const int bid = blockIdx.x;
    const bool modeV = bid < 612;

    const unsigned short* Bt;
    const float* bias;
    int M, N, rowBase, colBase;
    if (modeV) {
        Bt = BvalT; bias = b_value;
        M = BS * NV; N = 256;
        rowBase = (bid >> 1) * 128; colBase = (bid & 1) * 128;
    } else {
        const int b2 = bid - 612;
        Bt = BcatT; bias = biascat;
        M = BS * NQ; N = 768;
        rowBase = (b2 / 6) * 128; colBase = (b2 % 6) * 128;
    }

    const int t = threadIdx.x;
    const int w  = t >> 6;
    const int l  = t & 63;
    const int wm = (w >> 1) * 64;
    const int wn = (w & 1) * 64;
    const int row16 = l & 15;
    const int kg    = l >> 4;

    const int sr = t >> 1;        // tile row 0..127
    const int sh = t & 1;         // k half (16 elems)

    f32x4 acc[4][4] = {};

    for (int k0 = 0; k0 < 256; k0 += 32) {
        {   // A tile
            const int grow = rowBase + sr;
            short8 v0 = {}, v1 = {};
            if (modeV) {
                if (grow < M) {
                    const float* ap = valueF + (size_t)grow * 256 + k0 + sh * 16;
                    float va[16];
                    #pragma unroll
                    for (int jj = 0; jj < 4; jj++) {
                        const float4 f = *(const float4*)(ap + jj * 4);
                        va[jj*4+0]=f.x; va[jj*4+1]=f.y;
                        va[jj*4+2]=f.z; va[jj*4+3]=f.w;
                    }
                    #pragma unroll
                    for (int e = 0; e < 8; e++) {
                        v0[e] = (short)f2bf(va[e]);
                        v1[e] = (short)f2bf(va[8 + e]);
                    }
                }
            } else {
                if (grow < M) {
                    const unsigned short* ap =
                        querybf + (size_t)grow * 256 + k0 + sh * 16;
                    v0 = *(const short8*)ap;
                    v1 = *(const short8*)(ap + 8);
                }
            }
            Al[(sh * 2 + 0) * AST + sr] = v0;
            Al[(sh * 2 + 1) * AST + sr] = v1;
        }
        {   // B tile (B^T: always in-range)
            const unsigned short* bp = Bt + (size_t)(colBase + sr) * 256 + k0 + sh * 16;
            Bl[(sh * 2 + 0) * AST + sr] = *(const short8*)bp;
            Bl[(sh * 2 + 1) * AST + sr] = *(const short8*)(bp + 8);
        }
        __syncthreads();

        short8 af[4], bfr[4];
        #pragma unroll
        for (int i = 0; i < 4; i++) af[i] = Al[kg * AST + wm + i * 16 + row16];
        #pragma unroll
        for (int j = 0; j < 4; j++) bfr[j] = Bl[kg * AST + wn + j * 16 + row16];
        #pragma unroll
        for (int i = 0; i < 4; i++)
            #pragma unroll
            for (int j = 0; j < 4; j++)
                acc[i][j] = __builtin_amdgcn_mfma_f32_16x16x32_bf16(
                    bfr[j], af[i], acc[i][j], 0, 0, 0);
        __syncthreads();
    }

    const int m16 = l & 15;
    const int q4  = (l >> 4) * 4;
    #pragma unroll
    for (int i = 0; i < 4; i++) {
        const int row = rowBase + wm + i * 16 + m16;
        if (row >= M) continue;
        #pragma unroll
        for (int j = 0; j < 4; j++) {
            const int col0 = colBase + wn + j * 16 + q4;
            const float4 bv = *(const float4*)&bias[col0];
            half4v o;
            o[0] = (_Float16)(acc[i][j][0] + bv.x);
            o[1] = (_Float16)(acc[i][j][1] + bv.y);
            o[2] = (_Float16)(acc[i][j][2] + bv.z);
            o[3] = (_Float16)(acc[i][j][3] + bv.w);
            _Float16* dst;
            if (modeV) {
                const int b   = (row >= NV) ? 1 : 0;
                const int pix = row - b * NV;
                const int h   = col0 >> 5;
                const int ch  = col0 & 31;
                dst = vproj + ((size_t)(b * NH + h) * NV + pix) * 32 + ch;
            } else {
                dst = offcat + (size_t)row * 768 + col0;
            }
            *(half4v*)dst = o;
        }
    }
}

// ---------------------------------------------------------------------------
// Fused softmax + sampling + aggregation, (b,h)-partitioned for L2 locality.
// Phase B software-pipelined DEPTH 8: 8 addresses from LDS -> 8
// global_load_dwordx4 in flight -> consume (weights re-read from LDS to
// keep VGPR <= 64 at 8 blocks/CU). Desc stride 136 uint2: qi halves hit
// complementary LDS bank halves (conflict-free).
// ---------------------------------------------------------------------------
__global__ __launch_bounds__(256, 8) void sample_kernel(
    const _Float16* __restrict__ vproj,  // (BS, NH, NV, 32) f16
    const _Float16* __restrict__ offcat, // (BS*NQ, 768) f16 off|logits
    const float* __restrict__ refpts,    // (BS, NQ, 4, 2)
    float* __restrict__ out)             // (BS*NQ, 256)
{
    const int bid = blockIdx.x;
    const int h   = bid & 7;             // XCD-affine head
    const int g   = bid >> 3;
    const int b   = g & 1;
    const int q0  = (g >> 1) * 8;
    const int t   = threadIdx.x;

    __shared__ uint2 desc[8 * 136];      // [qi*136 + d*2 + pix]

    const int qi = t >> 5, j = t & 31;
    const int qrow = b * NQ + q0 + qi;

    // ---------------- Phase A ----------------
    {
        const int lv = j >> 3, p = j & 7;

        const float logit = (float)offcat[(size_t)qrow * 768 + 512 + h * 32 + j];
        const float e = __expf(logit);       // no max-pass: |logit| small
        float ssum = e;
        #pragma unroll
        for (int s = 16; s > 0; s >>= 1) ssum += __shfl_xor(ssum, s, 32);
        const float aw = e / ssum;

        const int Wl = LVL_W[lv], Hl = LVL_H[lv], st = LVL_START[lv];
        const uint oxy = *(const uint*)(offcat + (size_t)qrow * 768 + h * 64 + j * 2);
        const float offx = (float)__builtin_bit_cast(half2v, oxy)[0];
        const float offy = (float)__builtin_bit_cast(half2v, oxy)[1];

        const int z = p & 3;
        const float rx = refpts[((size_t)qrow * 4 + z) * 2];
        const float ry = refpts[((size_t)qrow * 4 + z) * 2 + 1];

        const float x = fmaf(rx, (float)Wl, offx) - 0.5f;
        const float y = fmaf(ry, (float)Hl, offy) - 0.5f;
        const float x0f = floorf(x), y0f = floorf(y);
        const float wx = x - x0f, wy = y - y0f;
        const int x0 = (int)x0f, y0 = (int)y0f;

        const int xb = min(max(x0, 0), Wl - 2);
        const float wl = (x0 >= 0 && x0 < Wl)          ? (1.f - wx) : 0.f;
        const float wr = (x0 + 1 >= 0 && x0 + 1 < Wl)  ? wx         : 0.f;
        const float wA = (x0 == xb) ? wl : ((x0 + 1 == xb) ? wr : 0.f);
        const float wB = (x0 == xb) ? wr : ((x0 == xb + 1) ? wl : 0.f);

        #pragma unroll
        for (int r = 0; r < 2; r++) {
            const int yy = y0 + r;
            const float rwv = (yy >= 0 && yy < Hl)
                            ? (r ? wy : (1.f - wy)) * aw : 0.f;
            const int iy = min(max(yy, 0), Hl - 1);
            const unsigned base = (unsigned)((st + iy * Wl + xb) * 64);
            uint4 dd;
            dd.x = base;      dd.y = f2h_dup(wA * rwv);
            dd.z = base + 64; dd.w = f2h_dup(wB * rwv);
            *(uint4*)&desc[qi * 136 + (j * 2 + r) * 2] = dd;
        }
    }
    __syncthreads();

    // ---------------- Phase B (pipelined depth 8) ----------------
    const int lane = t & 31;
    const int grp  = lane >> 3;          // descriptor stride group (bits 3-4)
    const int pix  = (lane >> 2) & 1;    // x-column (bit 2)
    const int chq  = lane & 3;           // channel quad (bits 0-1)

    const char* slab = (const char*)(vproj + (size_t)(b * NH + h) * NV * 32);
    const unsigned laneoff = (unsigned)(chq * 16);
    // dword view; desc i sits at dword (i*8)*2 relative to lane base
    const uint* dqw = (const uint*)&desc[qi * 136 + grp * 2 + pix];

    half2v a0 = {}, a1 = {}, a2 = {}, a3 = {};
    #pragma unroll
    for (int half = 0; half < 2; half++) {
        unsigned addr[8];
        #pragma unroll
        for (int u = 0; u < 8; u++)
            addr[u] = dqw[(half * 8 + u) * 16] + laneoff;
        uint4 v[8];
        #pragma unroll
        for (int u = 0; u < 8; u++)
            v[u] = *(const uint4*)(slab + addr[u]);
        #pragma unroll
        for (int u = 0; u < 8; u++) {
            const half2v wv = __builtin_bit_cast(half2v,
                                  dqw[(half * 8 + u) * 16 + 1]);
            a0 += wv * __builtin_bit_cast(half2v, v[u].x);  // v_pk_fma_f16
            a1 += wv * __builtin_bit_cast(half2v, v[u].y);
            a2 += wv * __builtin_bit_cast(half2v, v[u].z);
            a3 += wv * __builtin_bit_cast(half2v, v[u].w);
        }
    }

    // packed f16 reduce over bits 2,3,4 (pix + grp)
    #pragma unroll
    for (int s = 4; s <= 16; s <<= 1) {
        a0 += __builtin_bit_cast(half2v,
              __shfl_xor(__builtin_bit_cast(unsigned, a0), s, 32));
        a1 += __builtin_bit_cast(half2v,
              __shfl_xor(__builtin_bit_cast(unsigned, a1), s, 32));
        a2 += __builtin_bit_cast(half2v,
              __shfl_xor(__builtin_bit_cast(unsigned, a2), s, 32));
        a3 += __builtin_bit_cast(half2v,
              __shfl_xor(__builtin_bit_cast(unsigned, a3), s, 32));
    }

    if ((lane & 0x1C) == 0) {            // lanes 0..3 = chq
        float* op = out + (size_t)qrow * 256 + h * 32 + chq * 8;
        *(float4*)op = make_float4((float)a0[0], (float)a0[1],
                                   (float)a1[0], (float)a1[1]);
        *(float4*)(op + 4) = make_float4((float)a2[0], (float)a2[1],
                                         (float)a3[0], (float)a3[1]);
    }
}

// ---------------------------------------------------------------------------
extern "C" void kernel_launch(void* const* d_in, const int* in_sizes, int n_in,
                              void* d_out, int out_size, void* d_ws, size_t ws_size,
                              hipStream_t stream)
{
    const float* query   = (const float*)d_in[0];
    const float* value   = (const float*)d_in[1];
    const float* refpts  = (const float*)d_in[2];
    const float* W_value = (const float*)d_in[4];
    const float* b_value = (const float*)d_in[5];
    const float* W_off   = (const float*)d_in[6];
    const float* b_off   = (const float*)d_in[7];
    const float* W_attn  = (const float*)d_in[8];
    const float* b_attn  = (const float*)d_in[9];

    char* ws = (char*)d_ws;                       // total ~61.5 MB
    _Float16*       vproj   = (_Float16*)(ws);                    // 20,029,440
    unsigned short* querybf = (unsigned short*)(ws + 20029440);   // 10,240,000
    _Float16*       offcat  = (_Float16*)(ws + 30269440);         // 30,720,000
    unsigned short* BvalT   = (unsigned short*)(ws + 60989440);   //    131,072
    unsigned short* BcatT   = (unsigned short*)(ws + 61120512);   //    393,216
    float*          biascat = (float*)(ws + 61513728);            //      3,072

    const dim3 blk(256);

    prep_all<<<dim3(6025), blk, 0, stream>>>(
        query, W_value, W_off, b_off, W_attn, b_attn,
        querybf, BvalT, BcatT, biascat);

    gemm_all<<<dim3(1554), blk, 0, stream>>>(
        value, BvalT, b_value, vproj,
        querybf, BcatT, biascat, offcat);

    sample_kernel<<<dim3(BS * NQ), blk, 0, stream>>>(
        vproj, offcat, refpts, (float*)d_out);
}